// Round 7
// baseline (1521.565 us; speedup 1.0000x reference)
//
#include <hip/hip_runtime.h>

#define H    32
#define SEQ  1440
#define NT   (SEQ - 1)   // output steps s = 0..1438
#define NPH  SEQ         // pipeline phases p = 0..1439 (L1 lags L0 by one)
#define INP  11
#define TC   64          // x staging / FC chunk

#define LOG2E 1.44269504f

__device__ __forceinline__ float rcp_fast(float x)  { return __builtin_amdgcn_rcpf(x); }
__device__ __forceinline__ float exp2_fast(float x) { return __builtin_amdgcn_exp2f(x); }
__device__ __forceinline__ float tanh_f(float x) {
    // tanh(x) = 2/(1+exp2(-2*log2e*x)) - 1
    return fmaf(2.f, rcp_fast(1.f + exp2_fast(x * (-2.f * LOG2E))), -1.f);
}

// Block = 256 threads (4 waves) = one batch sample, layer-specialized:
//   threads   0..127 (half=0): layer-0 gate rows, weights wA=Whh0 row (32) + wB=Wih0 row (11)
//   threads 128..255 (half=1): layer-1 gate rows, weights wA=Wih1 row (32) + wB=Whh1 row (32)
// wA/wB are SHARED arrays across both divergent paths -> one register allocation
// (~64 weights + temps ~= 100 live regs, fits the ~112 the allocator grants ->
// no AGPR shuffling / reload bloat, which was 2.6x VALU issue in rounds 1-5).
// Pipeline: phase p: L0 computes h0[p] while L1 computes h1[p-1]. ONE barrier/phase.
// Parity rule: state[t] lives in buffer (t&1)^1; phase p reads h0[p-1] @ h0s[p&1].
__global__
__attribute__((amdgpu_flat_work_group_size(256, 256)))
__attribute__((amdgpu_waves_per_eu(2, 4)))
void lstm_fused_kernel(const float* __restrict__ x,
                       const float* __restrict__ Wih0, const float* __restrict__ Whh0,
                       const float* __restrict__ bih0, const float* __restrict__ bhh0,
                       const float* __restrict__ Wih1, const float* __restrict__ Whh1,
                       const float* __restrict__ bih1, const float* __restrict__ bhh1,
                       const float* __restrict__ fc1w_g, const float* __restrict__ fc1b_g,
                       const float* __restrict__ fc2w_g, const float* __restrict__ fc2b_g,
                       float* __restrict__ out)
{
    __shared__ float h0s[2][H];        // double-buffered layer-0 h
    __shared__ float h1s[2][H];        // double-buffered layer-1 h
    __shared__ float xs[TC][12];       // x chunk [pc][i], padded 11->12
    __shared__ float h1c[2][TC][36];   // h1 history, double-buffered by s-chunk parity

    const int tid  = threadIdx.x;
    const int half = tid >> 7;         // 0 = layer0 crew, 1 = layer1 crew
    const int ht   = tid & 127;
    const int l    = ht & 63;
    const int wv   = ht >> 6;          // wave within half
    const int m    = l & 15;
    const int q    = l >> 4;           // gate: 0=i 1=f 2=g 3=o
    const int jj   = wv * 16 + m;      // hidden unit
    const int r    = q * 32 + jj;      // weight row
    const int b    = blockIdx.x;

    const float gsl = ((q == 2) ? 2.f : 1.f) * LOG2E;  // fold tanh 2x + log2e
    const float am  = (q == 2) ? 2.f : 1.f;
    const float ab  = (q == 2) ? -1.f : 0.f;

    float wA[H], wB[H], bs;
    if (half == 0) {
        #pragma unroll
        for (int k = 0; k < H; ++k) wA[k] = Whh0[r * H + k] * gsl;
        #pragma unroll
        for (int i = 0; i < INP; ++i) wB[i] = Wih0[r * INP + i] * gsl;
        bs = (bih0[r] + bhh0[r]) * gsl;
    } else {
        #pragma unroll
        for (int k = 0; k < H; ++k) {
            wA[k] = Wih1[r * H + k] * gsl;
            wB[k] = Whh1[r * H + k] * gsl;
        }
        bs = (bih1[r] + bhh1[r]) * gsl;
    }

    if (tid < H)          h0s[0][tid] = 0.f;
    else if (tid < 2 * H) h1s[0][tid - H] = 0.f;
    float c = 0.f;   // c0 for L0 threads, c1 for L1 threads (q==0 lanes)

    const float* xb   = x   + (size_t)b * INP * SEQ;   // x[b][i][t], t contiguous
    float*       outb = out + (size_t)b * NT;

    for (int cb = 0; cb < NPH; cb += TC) {
        const int plen = min(TC, NPH - cb);

        // ---- stage x[b][:, cb:cb+plen] into LDS (coalesced over t) ----
        {
            const int col = tid & 63;
            const int rw  = tid >> 6;          // 0..3
            if (col < plen) {
                #pragma unroll
                for (int ib = 0; ib < 3; ++ib) {
                    const int row = ib * 4 + rw;
                    xs[col][row] = (row < INP) ? xb[row * SEQ + cb + col] : 0.f;
                }
            }
        }
        __syncthreads();

        for (int pc = 0; pc < plen; ++pc) {
            const int p = cb + pc;
            if (half == 0) {
                // ---- layer 0: compute h0[p] (skip dead final step) ----
                if (p < NT) {
                    const float4* xv = (const float4*)xs[pc];
                    const float4* hv = (const float4*)h0s[p & 1];   // h0[p-1]
                    float a0 = bs, a1 = 0.f;
                    float4 x0 = xv[0], x1 = xv[1], x2 = xv[2];
                    a0 = fmaf(wB[0],  x0.x, a0);  a1 = fmaf(wB[1],  x0.y, a1);
                    a0 = fmaf(wB[2],  x0.z, a0);  a1 = fmaf(wB[3],  x0.w, a1);
                    a0 = fmaf(wB[4],  x1.x, a0);  a1 = fmaf(wB[5],  x1.y, a1);
                    a0 = fmaf(wB[6],  x1.z, a0);  a1 = fmaf(wB[7],  x1.w, a1);
                    a0 = fmaf(wB[8],  x2.x, a0);  a1 = fmaf(wB[9],  x2.y, a1);
                    a0 = fmaf(wB[10], x2.z, a0);
                    #pragma unroll
                    for (int kk = 0; kk < 4; ++kk) {
                        float4 ha = hv[kk], hb = hv[kk + 4];
                        a0 = fmaf(wA[4*kk+0],    ha.x, a0);
                        a1 = fmaf(wA[4*kk+1],    ha.y, a1);
                        a0 = fmaf(wA[4*kk+2],    ha.z, a0);
                        a1 = fmaf(wA[4*kk+3],    ha.w, a1);
                        a0 = fmaf(wA[16+4*kk+0], hb.x, a0);
                        a1 = fmaf(wA[16+4*kk+1], hb.y, a1);
                        a0 = fmaf(wA[16+4*kk+2], hb.z, a0);
                        a1 = fmaf(wA[16+4*kk+3], hb.w, a1);
                    }
                    float a   = a0 + a1;
                    float act = fmaf(am, rcp_fast(1.f + exp2_fast(-a)), ab);
                    float gf = __shfl_xor(act, 16);
                    float gg = __shfl_xor(act, 32);
                    float go = __shfl_xor(act, 48);
                    if (q == 0) {
                        c = fmaf(gf, c, act * gg);
                        h0s[(p & 1) ^ 1][jj] = go * tanh_f(c);
                    }
                }
            } else {
                // ---- layer 1: compute h1[s], s = p-1 ----
                if (p >= 1) {
                    const int s = p - 1;
                    const float4* iv = (const float4*)h0s[p & 1];   // h0[s]
                    const float4* hv = (const float4*)h1s[s & 1];   // h1[s-1]
                    float a0 = bs, a1 = 0.f, a2 = 0.f, a3 = 0.f;
                    #pragma unroll
                    for (int kk = 0; kk < 4; ++kk) {
                        float4 ia = iv[kk], ia2 = iv[kk + 4];
                        float4 ha = hv[kk], ha2 = hv[kk + 4];
                        a0 = fmaf(wA[4*kk+0],    ia.x,  a0); a1 = fmaf(wA[4*kk+1],    ia.y,  a1);
                        a2 = fmaf(wA[4*kk+2],    ia.z,  a2); a3 = fmaf(wA[4*kk+3],    ia.w,  a3);
                        a0 = fmaf(wA[16+4*kk+0], ia2.x, a0); a1 = fmaf(wA[16+4*kk+1], ia2.y, a1);
                        a2 = fmaf(wA[16+4*kk+2], ia2.z, a2); a3 = fmaf(wA[16+4*kk+3], ia2.w, a3);
                        a0 = fmaf(wB[4*kk+0],    ha.x,  a0); a1 = fmaf(wB[4*kk+1],    ha.y,  a1);
                        a2 = fmaf(wB[4*kk+2],    ha.z,  a2); a3 = fmaf(wB[4*kk+3],    ha.w,  a3);
                        a0 = fmaf(wB[16+4*kk+0], ha2.x, a0); a1 = fmaf(wB[16+4*kk+1], ha2.y, a1);
                        a2 = fmaf(wB[16+4*kk+2], ha2.z, a2); a3 = fmaf(wB[16+4*kk+3], ha2.w, a3);
                    }
                    float a   = (a0 + a1) + (a2 + a3);
                    float act = fmaf(am, rcp_fast(1.f + exp2_fast(-a)), ab);
                    float gf = __shfl_xor(act, 16);
                    float gg = __shfl_xor(act, 32);
                    float go = __shfl_xor(act, 48);
                    if (q == 0) {
                        c = fmaf(gf, c, act * gg);
                        float hn = go * tanh_f(c);
                        h1s[(s & 1) ^ 1][jj] = hn;
                        h1c[(s >> 6) & 1][s & 63][jj] = hn;
                    }
                }
            }
            __syncthreads();   // the ONLY barrier per phase

            // ---- deferred FC for the just-completed previous s-chunk ----
            // s-chunk [cb-64, cb-1] finishes at pc=0 (lag 1); its h1c buffer is
            // the opposite parity of the writes during pc>=1 -> no extra barrier.
            if (pc == 0 && cb >= TC) {
                const float (*hc)[36] = h1c[((cb >> 6) - 1) & 1];
                const int u  = tid & 15;          // FC unit
                const int kh = (tid >> 4) & 1;    // k-half
                const int sl = tid >> 5;          // t-slot 0..7
                float fw[16];                      // chunk-local, not live in phases
                #pragma unroll
                for (int k = 0; k < 16; ++k) fw[k] = fc1w_g[u * H + kh * 16 + k];
                const float fb = fc1b_g[u], f2w = fc2w_g[u], f2b = fc2b_g[0];
                float* outc = outb + (cb - TC);
                #pragma unroll
                for (int rep = 0; rep < 8; ++rep) {
                    const int t2 = sl + 8 * rep;
                    const float4* hv = (const float4*)&hc[t2][kh * 16];
                    float a0 = 0.f, a1 = 0.f;
                    float4 v0 = hv[0], v1 = hv[1], v2 = hv[2], v3 = hv[3];
                    a0 = fmaf(fw[0],  v0.x, a0);  a1 = fmaf(fw[1],  v0.y, a1);
                    a0 = fmaf(fw[2],  v0.z, a0);  a1 = fmaf(fw[3],  v0.w, a1);
                    a0 = fmaf(fw[4],  v1.x, a0);  a1 = fmaf(fw[5],  v1.y, a1);
                    a0 = fmaf(fw[6],  v1.z, a0);  a1 = fmaf(fw[7],  v1.w, a1);
                    a0 = fmaf(fw[8],  v2.x, a0);  a1 = fmaf(fw[9],  v2.y, a1);
                    a0 = fmaf(fw[10], v2.z, a0);  a1 = fmaf(fw[11], v2.w, a1);
                    a0 = fmaf(fw[12], v3.x, a0);  a1 = fmaf(fw[13], v3.y, a1);
                    a0 = fmaf(fw[14], v3.z, a0);  a1 = fmaf(fw[15], v3.w, a1);
                    float y = a0 + a1;
                    y += __shfl_xor(y, 16);              // combine k-halves
                    float z = tanh_f(y + fb) * f2w;
                    z += __shfl_xor(z, 1);  z += __shfl_xor(z, 2);
                    z += __shfl_xor(z, 4);  z += __shfl_xor(z, 8);
                    if ((tid & 31) == 0) outc[t2] = z + f2b;
                }
            }
        }
    }

    // ---- tail FC: s in [1408, 1438] (31 entries), buffer (1408>>6)&1 = 0 ----
    {
        const int tbase = ((NPH - 1) / TC) * TC;          // 1408
        const int tlen  = NT - tbase;                     // 31
        const float (*hc)[36] = h1c[(tbase >> 6) & 1];
        const int u  = tid & 15;
        const int kh = (tid >> 4) & 1;
        const int sl = tid >> 5;
        float fw[16];
        #pragma unroll
        for (int k = 0; k < 16; ++k) fw[k] = fc1w_g[u * H + kh * 16 + k];
        const float fb = fc1b_g[u], f2w = fc2w_g[u], f2b = fc2b_g[0];
        float* outc = outb + tbase;
        #pragma unroll
        for (int rep = 0; rep < 8; ++rep) {
            const int t2 = sl + 8 * rep;
            if (t2 < tlen) {
                const float4* hv = (const float4*)&hc[t2][kh * 16];
                float a0 = 0.f, a1 = 0.f;
                float4 v0 = hv[0], v1 = hv[1], v2 = hv[2], v3 = hv[3];
                a0 = fmaf(fw[0],  v0.x, a0);  a1 = fmaf(fw[1],  v0.y, a1);
                a0 = fmaf(fw[2],  v0.z, a0);  a1 = fmaf(fw[3],  v0.w, a1);
                a0 = fmaf(fw[4],  v1.x, a0);  a1 = fmaf(fw[5],  v1.y, a1);
                a0 = fmaf(fw[6],  v1.z, a0);  a1 = fmaf(fw[7],  v1.w, a1);
                a0 = fmaf(fw[8],  v2.x, a0);  a1 = fmaf(fw[9],  v2.y, a1);
                a0 = fmaf(fw[10], v2.z, a0);  a1 = fmaf(fw[11], v2.w, a1);
                a0 = fmaf(fw[12], v3.x, a0);  a1 = fmaf(fw[13], v3.y, a1);
                a0 = fmaf(fw[14], v3.z, a0);  a1 = fmaf(fw[15], v3.w, a1);
                float y = a0 + a1;
                y += __shfl_xor(y, 16);
                float z = tanh_f(y + fb) * f2w;
                z += __shfl_xor(z, 1);  z += __shfl_xor(z, 2);
                z += __shfl_xor(z, 4);  z += __shfl_xor(z, 8);
                if ((tid & 31) == 0) outc[t2] = z + f2b;
            }
        }
    }
}

extern "C" void kernel_launch(void* const* d_in, const int* in_sizes, int n_in,
                              void* d_out, int out_size, void* d_ws, size_t ws_size,
                              hipStream_t stream)
{
    const float* x    = (const float*)d_in[0];
    const float* Wih0 = (const float*)d_in[1];
    const float* Whh0 = (const float*)d_in[2];
    const float* bih0 = (const float*)d_in[3];
    const float* bhh0 = (const float*)d_in[4];
    const float* Wih1 = (const float*)d_in[5];
    const float* Whh1 = (const float*)d_in[6];
    const float* bih1 = (const float*)d_in[7];
    const float* bhh1 = (const float*)d_in[8];
    const float* fc1w = (const float*)d_in[9];
    const float* fc1b = (const float*)d_in[10];
    const float* fc2w = (const float*)d_in[11];
    const float* fc2b = (const float*)d_in[12];
    float* out = (float*)d_out;

    const int B = in_sizes[0] / (INP * SEQ);   // 1024
    dim3 grid(B), block(256);
    hipLaunchKernelGGL(lstm_fused_kernel, grid, block, 0, stream,
                       x, Wih0, Whh0, bih0, bhh0, Wih1, Whh1, bih1, bhh1,
                       fc1w, fc1b, fc2w, fc2b, out);
}